// Round 1
// baseline (94.944 us; speedup 1.0000x reference)
//
#include <hip/hip_runtime.h>
#include <math.h>

#define BG 64
#define NN 2048
#define DD 128
#define KK 1024
#define EE 4194304

// out layout (all float32, return order):
//   [0]                x_out      B*K*D   = 8388608
//   [8388608]          edge_out   2*E     = 8388608
//   [16777216]         batch_out  B*K     = 65536
//   [16842752]         perm       B*K     = 65536
//   [16908288]         score_sel  B*K     = 65536
//   [16973824]         edge_mask  E       = 4194304
#define OFF_EI   8388608
#define OFF_BAT  16777216
#define OFF_PERM 16842752
#define OFF_SCR  16908288
#define OFF_MSK  16973824

// ---------- kernel 1: score = tanh((x.w)/||w||), one wave per node ----------
__global__ __launch_bounds__(256) void score_kernel(
    const float2* __restrict__ x2, const float2* __restrict__ w2,
    float* __restrict__ scores)
{
    int node = (blockIdx.x * 256 + threadIdx.x) >> 6;
    int lane = threadIdx.x & 63;
    float2 xv = x2[(size_t)node * 64 + lane];
    float2 wv = w2[lane];
    float dot = xv.x * wv.x + xv.y * wv.y;
    float ww  = wv.x * wv.x + wv.y * wv.y;
    #pragma unroll
    for (int off = 32; off >= 1; off >>= 1) {
        dot += __shfl_xor(dot, off);
        ww  += __shfl_xor(ww, off);
    }
    if (lane == 0) scores[node] = tanhf(dot / sqrtf(ww));
}

// monotone float<->uint order map (ascending)
__device__ __forceinline__ unsigned ford(float f) {
    unsigned b = __float_as_uint(f);
    return (b & 0x80000000u) ? ~b : (b | 0x80000000u);
}
__device__ __forceinline__ float forddec(unsigned u) {
    unsigned b = (u & 0x80000000u) ? (u & 0x7FFFFFFFu) : ~u;
    return __uint_as_float(b);
}

// ---------- kernel 2: per-graph bitonic sort (desc score, asc idx ties) ----------
// writes perm/score_sel/batch_out, perm_int (ws), and the full new_idx table
__global__ __launch_bounds__(1024) void sort_kernel(
    const float* __restrict__ scores,
    int* __restrict__ new_idx, int* __restrict__ perm_int,
    float* __restrict__ out_batch, float* __restrict__ out_perm,
    float* __restrict__ out_score)
{
    __shared__ unsigned long long keys[NN];
    const int b = blockIdx.x;
    const int t = threadIdx.x;

    #pragma unroll
    for (int i = t; i < NN; i += 1024) {
        float s = scores[b * NN + i];
        keys[i] = ((unsigned long long)ford(s) << 32) | (unsigned)(NN - 1 - i);
    }
    __syncthreads();

    // descending bitonic sort on u64 keys
    for (int k = 2; k <= NN; k <<= 1) {
        for (int j = k >> 1; j > 0; j >>= 1) {
            int i = ((t & ~(j - 1)) << 1) | (t & (j - 1));
            int p = i | j;
            unsigned long long a = keys[i], c = keys[p];
            bool sw = ((i & k) == 0) ? (a < c) : (a > c);
            if (sw) { keys[i] = c; keys[p] = a; }
            __syncthreads();
        }
    }

    // rank t (kept) and rank t+K (dropped)
    unsigned long long kk = keys[t];
    int idx  = NN - 1 - (int)(kk & 0xFFFFFFFFu);
    float s  = forddec((unsigned)(kk >> 32));
    int gid  = b * NN + idx;
    int row  = b * KK + t;
    new_idx[gid]   = row;
    perm_int[row]  = gid;
    out_perm[row]  = (float)gid;
    out_score[row] = s;
    out_batch[row] = (float)b;

    unsigned long long k2 = keys[t + KK];
    int idx2 = NN - 1 - (int)(k2 & 0xFFFFFFFFu);
    new_idx[b * NN + idx2] = -1;
}

// ---------- kernel 3: x_out[row] = x[perm[row]] * score_sel[row] ----------
__global__ __launch_bounds__(256) void gather_kernel(
    const float4* __restrict__ x4, const int* __restrict__ perm_int,
    const float* __restrict__ out_score, float4* __restrict__ xout4)
{
    int row  = blockIdx.x * 8 + (threadIdx.x >> 5);
    int lane = threadIdx.x & 31;
    int g    = perm_int[row];
    float s  = out_score[row];
    float4 v = x4[(size_t)g * 32 + lane];
    v.x *= s; v.y *= s; v.z *= s; v.w *= s;
    xout4[(size_t)row * 32 + lane] = v;
}

// ---------- kernel 4: relabel edges + mask ----------
__global__ __launch_bounds__(256) void edge_kernel(
    const int4* __restrict__ e0, const int4* __restrict__ e1,
    const int* __restrict__ new_idx,
    float4* __restrict__ oe0, float4* __restrict__ oe1,
    float4* __restrict__ omask)
{
    int i = blockIdx.x * 256 + threadIdx.x;  // [0, E/4)
    int4 r = e0[i];
    int4 c = e1[i];
    int nr0 = new_idx[r.x], nr1 = new_idx[r.y], nr2 = new_idx[r.z], nr3 = new_idx[r.w];
    int nc0 = new_idx[c.x], nc1 = new_idx[c.y], nc2 = new_idx[c.z], nc3 = new_idx[c.w];
    bool m0 = (nr0 >= 0) & (nc0 >= 0);
    bool m1 = (nr1 >= 0) & (nc1 >= 0);
    bool m2 = (nr2 >= 0) & (nc2 >= 0);
    bool m3 = (nr3 >= 0) & (nc3 >= 0);
    oe0[i]   = make_float4(m0 ? (float)nr0 : 0.0f, m1 ? (float)nr1 : 0.0f,
                           m2 ? (float)nr2 : 0.0f, m3 ? (float)nr3 : 0.0f);
    oe1[i]   = make_float4(m0 ? (float)nc0 : 0.0f, m1 ? (float)nc1 : 0.0f,
                           m2 ? (float)nc2 : 0.0f, m3 ? (float)nc3 : 0.0f);
    omask[i] = make_float4(m0 ? 1.0f : 0.0f, m1 ? 1.0f : 0.0f,
                           m2 ? 1.0f : 0.0f, m3 ? 1.0f : 0.0f);
}

extern "C" void kernel_launch(void* const* d_in, const int* in_sizes, int n_in,
                              void* d_out, int out_size, void* d_ws, size_t ws_size,
                              hipStream_t stream)
{
    const float* x  = (const float*)d_in[0];   // [B*N, D]
    const int*   ei = (const int*)d_in[1];     // [2, E]
    // d_in[2] = batch (unused: regular graphs), d_in[3] = w
    const float* w  = (const float*)d_in[3];   // [D]
    float* out = (float*)d_out;

    // ws layout: scores [B*N f32] | new_idx [B*N i32] | perm_int [B*K i32]
    float* scores  = (float*)d_ws;
    int*   new_idx = (int*)d_ws + BG * NN;
    int*   perm_i  = (int*)d_ws + 2 * BG * NN;

    // 1) scores
    score_kernel<<<BG * NN / 4, 256, 0, stream>>>(
        (const float2*)x, (const float2*)w, scores);

    // 2) per-graph sort + selection outputs + relabel table
    sort_kernel<<<BG, 1024, 0, stream>>>(
        scores, new_idx, perm_i,
        out + OFF_BAT, out + OFF_PERM, out + OFF_SCR);

    // 3) gated feature gather
    gather_kernel<<<BG * KK / 8, 256, 0, stream>>>(
        (const float4*)x, perm_i, out + OFF_SCR, (float4*)out);

    // 4) edge relabel + mask
    edge_kernel<<<EE / 4 / 256, 256, 0, stream>>>(
        (const int4*)ei, (const int4*)(ei + EE), new_idx,
        (float4*)(out + OFF_EI), (float4*)(out + OFF_EI + EE),
        (float4*)(out + OFF_MSK));
}

// Round 2
// 71.537 us; speedup vs baseline: 1.3272x; 1.3272x over previous
//
#include <hip/hip_runtime.h>
#include <math.h>

#define BG 64
#define NN 2048
#define DD 128
#define KK 1024
#define EE 4194304

// out layout (all float32, return order):
#define OFF_EI   8388608
#define OFF_BAT  16777216
#define OFF_PERM 16842752
#define OFF_SCR  16908288
#define OFF_MSK  16973824

#define EDGE_BLOCKS   2048   // E / (256*8)
#define GATHER_BLOCKS 8192   // B*K / 8

typedef unsigned long long u64;
typedef float f4v __attribute__((ext_vector_type(4)));

__device__ __forceinline__ void nt_store4(float a, float b, float c, float d, float* p) {
    f4v v = {a, b, c, d};
    __builtin_nontemporal_store(v, (f4v*)p);
}

// ---------- kernel 1: score = tanh((x.w)/||w||), one wave per node ----------
// (kept byte-identical: its rounding defines the top-k tie behavior)
__global__ __launch_bounds__(256) void score_kernel(
    const float2* __restrict__ x2, const float2* __restrict__ w2,
    float* __restrict__ scores)
{
    int node = (blockIdx.x * 256 + threadIdx.x) >> 6;
    int lane = threadIdx.x & 63;
    float2 xv = x2[(size_t)node * 64 + lane];
    float2 wv = w2[lane];
    float dot = xv.x * wv.x + xv.y * wv.y;
    float ww  = wv.x * wv.x + wv.y * wv.y;
    #pragma unroll
    for (int off = 32; off >= 1; off >>= 1) {
        dot += __shfl_xor(dot, off);
        ww  += __shfl_xor(ww, off);
    }
    if (lane == 0) scores[node] = tanhf(dot / sqrtf(ww));
}

// monotone float<->uint order map (ascending)
__device__ __forceinline__ unsigned ford(float f) {
    unsigned b = __float_as_uint(f);
    return (b & 0x80000000u) ? ~b : (b | 0x80000000u);
}
__device__ __forceinline__ float forddec(unsigned u) {
    unsigned b = (u & 0x80000000u) ? (u & 0x7FFFFFFFu) : ~u;
    return __uint_as_float(b);
}

// bitonic compare-exchange via cross-lane shuffle (element held in register)
__device__ __forceinline__ u64 regswap(u64 v, int elem_idx, int j, int k) {
    u64 p = __shfl_xor(v, j, 64);
    bool dir   = ((elem_idx & k) == 0);   // true -> descending region
    bool lower = ((elem_idx & j) == 0);
    return (dir == lower) ? (v > p ? v : p) : (v < p ? v : p);
}

// ---------- kernel 2: per-graph bitonic sort (desc score, asc idx ties) ----------
// writes perm/score_sel/batch_out, perm_int, 16-bit rank table, kept-bitmask
__global__ __launch_bounds__(1024) void sort_kernel(
    const float* __restrict__ scores,
    int* __restrict__ perm_int, unsigned short* __restrict__ tab16,
    unsigned* __restrict__ maskbits,
    float* __restrict__ out_batch, float* __restrict__ out_perm,
    float* __restrict__ out_score)
{
    __shared__ u64 keys[NN];
    __shared__ unsigned mw[NN / 32];
    const int b = blockIdx.x;
    const int t = threadIdx.x;

    float s0 = scores[b * NN + t];
    float s1 = scores[b * NN + 1024 + t];
    u64 va = ((u64)ford(s0) << 32) | (unsigned)(NN - 1 - t);
    u64 vb = ((u64)ford(s1) << 32) | (unsigned)(NN - 1 - (1024 + t));

    // stages k=2..64: entirely intra-wave, no barriers
    #pragma unroll
    for (int k = 2; k <= 64; k <<= 1)
        #pragma unroll
        for (int j = k >> 1; j >= 1; j >>= 1) {
            va = regswap(va, t, j, k);
            vb = regswap(vb, 1024 + t, j, k);
        }

    keys[t] = va; keys[1024 + t] = vb;
    if (t < NN / 32) mw[t] = 0u;
    __syncthreads();

    for (int k = 128; k <= 2048; k <<= 1) {
        // cross-wave exchanges through LDS (j >= 64)
        for (int j = k >> 1; j >= 64; j >>= 1) {
            int i = ((t & ~(j - 1)) << 1) | (t & (j - 1));
            int p = i | j;
            u64 A = keys[i], C = keys[p];
            bool sw = ((i & k) == 0) ? (A < C) : (A > C);
            if (sw) { keys[i] = C; keys[p] = A; }
            __syncthreads();
        }
        // intra-wave tail (j = 32..1) in registers
        va = keys[t]; vb = keys[1024 + t];
        #pragma unroll
        for (int j = 32; j >= 1; j >>= 1) {
            va = regswap(va, t, j, k);
            vb = regswap(vb, 1024 + t, j, k);
        }
        if (k < 2048) {                    // final stage: result consumed from va
            keys[t] = va; keys[1024 + t] = vb;
            __syncthreads();
        }
    }

    // thread t holds the rank-t (kept) element in va; rank t+K (vb) is dropped
    int idx  = NN - 1 - (int)(va & 0xFFFFFFFFu);
    float s  = forddec((unsigned)(va >> 32));
    int gid  = b * NN + idx;
    int row  = b * KK + t;
    perm_int[row]  = gid;
    tab16[gid]     = (unsigned short)t;
    out_perm[row]  = (float)gid;
    out_score[row] = s;
    out_batch[row] = (float)b;
    atomicOr(&mw[idx >> 5], 1u << (idx & 31));
    __syncthreads();
    if (t < NN / 32) maskbits[b * (NN / 32) + t] = mw[t];
}

// ---------- fused kernel 3: edge relabel+mask (blocks [0,2048)) + x gather ----------
__device__ __forceinline__ void edge1(int r, int c,
    const unsigned* __restrict__ mb, const unsigned short* __restrict__ tab,
    float& er, float& ec, float& em)
{
    unsigned m = (mb[(unsigned)r >> 5] >> (r & 31)) &
                 (mb[(unsigned)c >> 5] >> (c & 31)) & 1u;
    int nr = 0, nc = 0;
    if (m) {
        nr = ((r >> 11) << 10) + tab[r];
        nc = ((c >> 11) << 10) + tab[c];
    }
    er = (float)nr; ec = (float)nc; em = m ? 1.0f : 0.0f;
}

__global__ __launch_bounds__(256) void tail_kernel(
    const int4* __restrict__ e0, const int4* __restrict__ e1,
    const unsigned* __restrict__ mb, const unsigned short* __restrict__ tab,
    const float4* __restrict__ x4, const int* __restrict__ perm_int,
    const float* __restrict__ out_score, float* __restrict__ out)
{
    int bid = blockIdx.x;
    if (bid < EDGE_BLOCKS) {
        float* oe0 = out + OFF_EI;
        float* oe1 = out + OFF_EI + EE;
        float* om  = out + OFF_MSK;
        int base = bid * 512 + threadIdx.x;
        #pragma unroll
        for (int u = 0; u < 2; ++u) {
            int i = base + u * 256;
            int4 r = e0[i];
            int4 c = e1[i];
            float r0, r1, r2, r3, c0, c1, c2, c3, m0, m1, m2, m3;
            edge1(r.x, c.x, mb, tab, r0, c0, m0);
            edge1(r.y, c.y, mb, tab, r1, c1, m1);
            edge1(r.z, c.z, mb, tab, r2, c2, m2);
            edge1(r.w, c.w, mb, tab, r3, c3, m3);
            nt_store4(r0, r1, r2, r3, oe0 + 4 * (size_t)i);
            nt_store4(c0, c1, c2, c3, oe1 + 4 * (size_t)i);
            nt_store4(m0, m1, m2, m3, om  + 4 * (size_t)i);
        }
    } else {
        int gb   = bid - EDGE_BLOCKS;
        int row  = gb * 8 + (threadIdx.x >> 5);
        int lane = threadIdx.x & 31;
        int g    = perm_int[row];
        float s  = out_score[row];
        float4 v = x4[(size_t)g * 32 + lane];
        nt_store4(v.x * s, v.y * s, v.z * s, v.w * s,
                  out + ((size_t)row * 32 + lane) * 4);
    }
}

extern "C" void kernel_launch(void* const* d_in, const int* in_sizes, int n_in,
                              void* d_out, int out_size, void* d_ws, size_t ws_size,
                              hipStream_t stream)
{
    const float* x  = (const float*)d_in[0];   // [B*N, D]
    const int*   ei = (const int*)d_in[1];     // [2, E]
    const float* w  = (const float*)d_in[3];   // [D]
    float* out = (float*)d_out;

    // ws layout: scores f32[B*N] | perm_int i32[B*K] | tab16 u16[B*N] | maskbits u32[B*N/32]
    float*          scores   = (float*)d_ws;
    int*            perm_i   = (int*)d_ws + BG * NN;
    unsigned short* tab16    = (unsigned short*)((char*)d_ws + (BG * NN + BG * KK) * 4);
    unsigned*       maskbits = (unsigned*)((char*)d_ws + (BG * NN + BG * KK) * 4 + BG * NN * 2);

    score_kernel<<<BG * NN / 4, 256, 0, stream>>>(
        (const float2*)x, (const float2*)w, scores);

    sort_kernel<<<BG, 1024, 0, stream>>>(
        scores, perm_i, tab16, maskbits,
        out + OFF_BAT, out + OFF_PERM, out + OFF_SCR);

    tail_kernel<<<EDGE_BLOCKS + GATHER_BLOCKS, 256, 0, stream>>>(
        (const int4*)ei, (const int4*)(ei + EE), maskbits, tab16,
        (const float4*)x, perm_i, out + OFF_SCR, out);
}